// Round 2
// baseline (1068.587 us; speedup 1.0000x reference)
//
#include <hip/hip_runtime.h>
#include <stdint.h>

// ---------------- types ----------------
typedef __attribute__((ext_vector_type(8))) short short8;   // 8 x bf16 (4 VGPR) MFMA A/B frag
typedef __attribute__((ext_vector_type(4))) short short4v;  // 8B packed LDS write
typedef __attribute__((ext_vector_type(4))) float float4v;  // MFMA C/D frag

__device__ __forceinline__ short f2bf(float f) {
  uint32_t u = __builtin_bit_cast(uint32_t, f);
  u += 0x7FFFu + ((u >> 16) & 1u);   // round-to-nearest-even
  return (short)(u >> 16);
}

// async global->LDS, 16B per lane, wave-uniform LDS base
__device__ __forceinline__ void gl_lds16(const short* g, short* l) {
  __builtin_amdgcn_global_load_lds(
      (const __attribute__((address_space(1))) unsigned int*)g,
      (__attribute__((address_space(3))) unsigned int*)l, 16, 0, 0);
}

// =====================================================================
// LDS swizzle scheme (all row-major short buffers, 16B-unit XOR):
//   element (row, k) stored at row*RS + (k ^ ((row&7)<<3))   [k in shorts]
// For b128 reads at k = 32*j + 8*quad the swizzled offset splits as
//   64*(jlsb ^ (r>>2)) + 8*(quad ^ (r&3)) + 64*(j>>1)*? ...
// which is handled with TWO per-lane bases (even/odd j):
//   offE = ((quad ^ (r&3))<<3) | ((r>>2)<<5),  offO = offE ^ 32,  r = l16&7
// so every ds_read is base + compile-time immediate (no carry into XOR bits).
// Verified: lanes sharing a 16B unit-class have distinct rows spread across
// all 32 banks -> conflict-free minimum for wave64 b128.
// =====================================================================

// =====================================================================
// Kernel 1: convert weights to bf16 in workspace
// =====================================================================
__global__ void prep_weights(const float* __restrict__ wq, const float* __restrict__ wp,
                             short* __restrict__ wq_b, short* __restrict__ wp_b) {
  int i = blockIdx.x * blockDim.x + threadIdx.x;
  int stride = gridDim.x * blockDim.x;
  for (int j = i; j < 786432 / 4; j += stride) {
    float4 v = ((const float4*)wq)[j];
    short4v t = {f2bf(v.x), f2bf(v.y), f2bf(v.z), f2bf(v.w)};
    ((short4v*)wq_b)[j] = t;
  }
  for (int j = i; j < 262144 / 4; j += stride) {
    float4 v = ((const float4*)wp)[j];
    short4v t = {f2bf(v.x), f2bf(v.y), f2bf(v.z), f2bf(v.w)};
    ((short4v*)wp_b)[j] = t;
  }
}

// =====================================================================
// Kernel 2: fused QKV-GEMM + window attention.  1 block = 1 window.
// 1024 threads = 16 waves (4 waves/SIMD -- double round-1 occupancy).
// 2 rounds of 4 heads:
//   phase1: wave (g = w>>2, st = w&3) computes the merged {Qt,Kt,V} strip
//     triple: Q/V head h0+g, K head h0+(g^1), strip st.  One K-loop, 3 acc
//     sets: 4 ds_read_b128 per 12 MFMA.
//   phase2: wave -> (head hsel = w>>2, 16-row strip n0): S=Q*K^T + analytic
//     earth bias, shfl softmax, P->Qs (wave-local), O=P*Vt, bf16 store.
// LDS: Xs 64K + Qs/Ks/Vt 4 heads x 8K each = 163,840 B (exactly 160 KB).
// All buffers unpadded + XOR-swizzled (conflict-free, see scheme above).
// =====================================================================
__global__ __launch_bounds__(1024, 4)
void qkv_attn(const float* __restrict__ x, const short* __restrict__ wq,
              const float* __restrict__ bqkv, const float* __restrict__ btab,
              short* __restrict__ attn) {
  __shared__ short Xs[64 * 512];        // 65,536 B
  __shared__ short Qs[4][64 * 64];      // 32,768 B
  __shared__ short Ks[4][64 * 64];      // 32,768 B
  __shared__ short Vt[4][64 * 64];      // 32,768 B   total 163,840 B

  const int b    = blockIdx.x;
  const int tid  = threadIdx.x;
  const int lane = tid & 63;
  const int w    = tid >> 6;       // wave 0..15
  const int l16  = lane & 15;
  const int quad = lane >> 4;      // 0..3
  const int lat  = b >> 6;         // MLON = 64
  const int r    = l16 & 7;
  const int offE = ((quad ^ (r & 3)) << 3) | ((r >> 2) << 5);
  const int offO = offE ^ 32;

  // ---- stage X window into LDS as bf16 (swizzled write) ----
  const float* xw = x + (size_t)b * (64 * 512);
  for (int c = tid; c < 64 * 128; c += 1024) {   // float4 chunks
    int n = c >> 7, kc = c & 127;
    float4 v = *(const float4*)(xw + n * 512 + kc * 4);
    short4v t = {f2bf(v.x), f2bf(v.y), f2bf(v.z), f2bf(v.w)};
    *(short4v*)&Xs[n * 512 + ((kc * 4) ^ ((n & 7) << 3))] = t;
  }
  __syncthreads();

  const int g  = w >> 2;   // head offset within round (Q,V) ; K head = g^1
  const int st = w & 3;    // 16-row strip

#pragma unroll 1
  for (int h0 = 0; h0 < 8; h0 += 4) {
    // ---------------- phase 1: QKV GEMMs (strip-merged) ----------------
    {
      const int hq = h0 + g;
      const int hk = h0 + (g ^ 1);
      const short* Aq = wq + (size_t)((hq * 64 + st * 16 + l16) * 512) + quad * 8;
      const short* Ak = wq + (size_t)((512 + hk * 64 + st * 16 + l16) * 512) + quad * 8;
      const short* Av = wq + (size_t)((1024 + hq * 64 + st * 16 + l16) * 512) + quad * 8;
      const short* xE = &Xs[l16 * 512 + offE];
      const short* xO = &Xs[l16 * 512 + offO];

      float4v aQ[4] = {}, aK[4] = {}, aV[4] = {};
#pragma unroll
      for (int j = 0; j < 16; ++j) {            // kk = j*32
        const short* xb = (j & 1) ? xO : xE;
        const int xoff = (j >> 1) * 64;
        short8 wqf = *(const short8*)(Aq + j * 32);
        short8 wkf = *(const short8*)(Ak + j * 32);
        short8 wvf = *(const short8*)(Av + j * 32);
        short8 x0 = *(const short8*)(xb + xoff);
        short8 x1 = *(const short8*)(xb + 8192 + xoff);
        short8 x2 = *(const short8*)(xb + 16384 + xoff);
        short8 x3 = *(const short8*)(xb + 24576 + xoff);
        aQ[0] = __builtin_amdgcn_mfma_f32_16x16x32_bf16(wqf, x0, aQ[0], 0, 0, 0);
        aQ[1] = __builtin_amdgcn_mfma_f32_16x16x32_bf16(wqf, x1, aQ[1], 0, 0, 0);
        aQ[2] = __builtin_amdgcn_mfma_f32_16x16x32_bf16(wqf, x2, aQ[2], 0, 0, 0);
        aQ[3] = __builtin_amdgcn_mfma_f32_16x16x32_bf16(wqf, x3, aQ[3], 0, 0, 0);
        aK[0] = __builtin_amdgcn_mfma_f32_16x16x32_bf16(wkf, x0, aK[0], 0, 0, 0);
        aK[1] = __builtin_amdgcn_mfma_f32_16x16x32_bf16(wkf, x1, aK[1], 0, 0, 0);
        aK[2] = __builtin_amdgcn_mfma_f32_16x16x32_bf16(wkf, x2, aK[2], 0, 0, 0);
        aK[3] = __builtin_amdgcn_mfma_f32_16x16x32_bf16(wkf, x3, aK[3], 0, 0, 0);
        aV[0] = __builtin_amdgcn_mfma_f32_16x16x32_bf16(x0, wvf, aV[0], 0, 0, 0);
        aV[1] = __builtin_amdgcn_mfma_f32_16x16x32_bf16(x1, wvf, aV[1], 0, 0, 0);
        aV[2] = __builtin_amdgcn_mfma_f32_16x16x32_bf16(x2, wvf, aV[2], 0, 0, 0);
        aV[3] = __builtin_amdgcn_mfma_f32_16x16x32_bf16(x3, wvf, aV[3], 0, 0, 0);
      }

      // ---- epilogues (identical math; swizzled LDS writes) ----
      float bq[4], bk[4];
#pragma unroll
      for (int i = 0; i < 4; ++i) {
        bq[i] = bqkv[hq * 64 + st * 16 + quad * 4 + i];
        bk[i] = bqkv[512 + hk * 64 + st * 16 + quad * 4 + i];
      }
      short* dq = &Qs[g][0];
      short* dk = &Ks[g ^ 1][0];
      const int swqk = (st * 16 + quad * 4) ^ (r << 3);   // row&7 == r for rows t*16+l16
#pragma unroll
      for (int t = 0; t < 4; ++t) {
        int n = t * 16 + l16;
        short4v pq, pk;
#pragma unroll
        for (int i = 0; i < 4; ++i) {
          pq[i] = f2bf((aQ[t][i] + bq[i]) * 0.125f);   // fold q-scale (exact pow2)
          pk[i] = f2bf(aK[t][i] + bk[i]);
        }
        *(short4v*)&dq[n * 64 + swqk] = pq;  // [n][d] packed, swizzled
        *(short4v*)&dk[n * 64 + swqk] = pk;
      }
      float bv = bqkv[1024 + hq * 64 + st * 16 + l16];
      const int dv = st * 16 + l16;          // Vt row (= d); dv&7 == r
#pragma unroll
      for (int t = 0; t < 4; ++t) {
        short4v pv;
#pragma unroll
        for (int i = 0; i < 4; ++i) pv[i] = f2bf(aV[t][i] + bv);
        *(short4v*)&Vt[g][dv * 64 + ((t * 16 + quad * 4) ^ (r << 3))] = pv;  // [d][m]
      }
    }
    __syncthreads();

    // ---------------- phase 2: attention ----------------
    {
      const int hsel = w >> 2;
      const int h    = h0 + hsel;
      const int n0   = (w & 3) * 16;
      const short* Qb = &Qs[hsel][0];
      const short* Kb = &Ks[hsel][0];
      const short* Vb = &Vt[hsel][0];

      // S = Q * K^T  (K-dim = d = 64)
      float4v s4[4] = {};
#pragma unroll
      for (int j = 0; j < 2; ++j) {
        const int o = j ? offO : offE;
        short8 a = *(const short8*)&Qb[(n0 + l16) * 64 + o];
#pragma unroll
        for (int t = 0; t < 4; ++t) {
          short8 bf = *(const short8*)&Kb[(t * 16 + l16) * 64 + o];
          s4[t] = __builtin_amdgcn_mfma_f32_16x16x32_bf16(a, bf, s4[t], 0, 0, 0);
        }
      }
      // analytic earth bias (skips rel_idx input entirely)
#pragma unroll
      for (int t = 0; t < 4; ++t) {
        int m = t * 16 + l16;
#pragma unroll
        for (int i = 0; i < 4; ++i) {
          int n = n0 + quad * 4 + i;
          int idx = ((n >> 3) - (m >> 3) + 7) * 15 + ((n & 7) - (m & 7) + 7) + lat * 225;
          s4[t][i] += btab[idx * 8 + h];
        }
      }
      // row softmax: row n held at fixed reg i across 16 lanes of the quad
      float p[4][4];
#pragma unroll
      for (int i = 0; i < 4; ++i) {
        float mx = fmaxf(fmaxf(s4[0][i], s4[1][i]), fmaxf(s4[2][i], s4[3][i]));
        mx = fmaxf(mx, __shfl_xor(mx, 1));
        mx = fmaxf(mx, __shfl_xor(mx, 2));
        mx = fmaxf(mx, __shfl_xor(mx, 4));
        mx = fmaxf(mx, __shfl_xor(mx, 8));
        float e0 = __expf(s4[0][i] - mx), e1 = __expf(s4[1][i] - mx);
        float e2 = __expf(s4[2][i] - mx), e3 = __expf(s4[3][i] - mx);
        float sm = e0 + e1 + e2 + e3;
        sm += __shfl_xor(sm, 1);
        sm += __shfl_xor(sm, 2);
        sm += __shfl_xor(sm, 4);
        sm += __shfl_xor(sm, 8);
        float inv = 1.0f / sm;
        p[0][i] = e0 * inv; p[1][i] = e1 * inv; p[2][i] = e2 * inv; p[3][i] = e3 * inv;
      }
      // P -> LDS (overwrite own Q rows; wave-local round trip -- no barrier)
      short* Pw = &Qs[hsel][0];
#pragma unroll
      for (int t = 0; t < 4; ++t)
#pragma unroll
        for (int i = 0; i < 4; ++i) {
          int row = n0 + quad * 4 + i;
          Pw[row * 64 + ((t * 16 + l16) ^ ((row & 7) << 3))] = f2bf(p[t][i]);
        }

      // O = P * V  (K-dim = m = 64)
      float4v o4[4] = {};
#pragma unroll
      for (int j = 0; j < 2; ++j) {
        const int o = j ? offO : offE;
        short8 a = *(const short8*)&Qb[(n0 + l16) * 64 + o];
#pragma unroll
        for (int t = 0; t < 4; ++t) {
          short8 bf = *(const short8*)&Vb[(t * 16 + l16) * 64 + o];
          o4[t] = __builtin_amdgcn_mfma_f32_16x16x32_bf16(a, bf, o4[t], 0, 0, 0);
        }
      }
      // store attn[b][n][h*64 + d] as bf16
      short* ob = attn + (size_t)b * (64 * 512);
#pragma unroll
      for (int t = 0; t < 4; ++t)
#pragma unroll
        for (int i = 0; i < 4; ++i)
          ob[(n0 + quad * 4 + i) * 512 + h * 64 + t * 16 + l16] = f2bf(o4[t][i]);
    }
    __syncthreads();   // protect Qs/Ks/Vt before next head round
  }
}

// =====================================================================
// Kernel 3: out = attn(131072x512 bf16) @ w_proj^T + b_proj   (fp32 out)
// 128x128 tile, BK=64, 512 threads (8 waves, 32x64 per wave).
// Double-buffered global_load_lds with stage-ahead (T3-minimum pipeline);
// both-sides swizzle: linear LDS dest + inverse-swizzled GLOBAL source col,
// swizzled ds_read -> conflict-free (fixes the 16-way [row][64] conflict).
// 64 KB LDS + VGPR<=128 -> 2 blocks/CU = 4 waves/SIMD.
// =====================================================================
__device__ __forceinline__ void stage_tile(const short* __restrict__ ga,
                                           const short* __restrict__ gb,
                                           short* lA, short* lB,
                                           int w, int srow, int scol) {
#pragma unroll
  for (int j = 0; j < 2; ++j) {
    int c = w * 2 + j;   // chunk 0..15, 8 rows each
    gl_lds16(ga + (size_t)(c * 8 + srow) * 512 + scol, &lA[c * 512]);
    gl_lds16(gb + (size_t)(c * 8 + srow) * 512 + scol, &lB[c * 512]);
  }
}

__device__ __forceinline__ void compute_tile(const short* As_, const short* Bs_,
                                             float4v (&acc)[2][4],
                                             int wm, int wn, int l16,
                                             int offE, int offO) {
#pragma unroll
  for (int ks = 0; ks < 2; ++ks) {
    const int o = ks ? offO : offE;
    short8 a[2], bf[4];
#pragma unroll
    for (int ti = 0; ti < 2; ++ti)
      a[ti] = *(const short8*)&As_[(wm * 32 + ti * 16 + l16) * 64 + o];
#pragma unroll
    for (int tj = 0; tj < 4; ++tj)
      bf[tj] = *(const short8*)&Bs_[(wn * 64 + tj * 16 + l16) * 64 + o];
#pragma unroll
    for (int ti = 0; ti < 2; ++ti)
#pragma unroll
      for (int tj = 0; tj < 4; ++tj)
        acc[ti][tj] = __builtin_amdgcn_mfma_f32_16x16x32_bf16(a[ti], bf[tj], acc[ti][tj], 0, 0, 0);
  }
}

__global__ __launch_bounds__(512, 4)
void proj_gemm(const short* __restrict__ attn, const short* __restrict__ wp,
               const float* __restrict__ bproj, float* __restrict__ out) {
  __shared__ short As0[128 * 64];   // 16 KB each; named buffers so alias
  __shared__ short As1[128 * 64];   // analysis lets ds_read(cur) bypass the
  __shared__ short Bs0[128 * 64];   // in-flight gl_lds(next) -> overlap.
  __shared__ short Bs1[128 * 64];   // total 64 KB -> 2 blocks/CU

  // XCD-bijective remap (nwg=4096 = 8*512): wg = xcd*512 + orig/8
  const int orig = blockIdx.x;
  const int wg   = (orig & 7) * 512 + (orig >> 3);
  const int n0   = (wg & 3) * 128;   // n fastest: 4 n-blocks share an A-panel
  const int m0   = (wg >> 2) * 128;

  const int tid  = threadIdx.x;
  const int lane = tid & 63;
  const int w    = tid >> 6;           // 0..7
  const int l16  = lane & 15;
  const int quad = lane >> 4;
  const int wm   = w >> 1, wn = w & 1; // wave tile: rows wm*32, cols wn*64
  const int r    = l16 & 7;
  const int offE = ((quad ^ (r & 3)) << 3) | ((r >> 2) << 5);
  const int offO = offE ^ 32;

  // staging: lane -> (srow, swizzled global col) so LINEAR lds dest yields
  // the swizzled layout: slot (row, s) holds element k = s ^ ((row&7)<<3)
  const int srow = lane >> 3;                       // 0..7 (== row&7)
  const int scol = ((lane & 7) ^ srow) * 8;         // shorts

  const short* gA = attn + (size_t)m0 * 512;
  const short* gB = wp + (size_t)n0 * 512;

  float4v acc[2][4] = {};

  stage_tile(gA, gB, As0, Bs0, w, srow, scol);
  __syncthreads();
#pragma unroll
  for (int kt = 0; kt < 8; kt += 2) {
    if (kt + 1 < 8) stage_tile(gA + (kt + 1) * 64, gB + (kt + 1) * 64, As1, Bs1, w, srow, scol);
    compute_tile(As0, Bs0, acc, wm, wn, l16, offE, offO);
    __syncthreads();
    if (kt + 2 < 8) stage_tile(gA + (kt + 2) * 64, gB + (kt + 2) * 64, As0, Bs0, w, srow, scol);
    compute_tile(As1, Bs1, acc, wm, wn, l16, offE, offO);
    __syncthreads();
  }

  float bj[4];
#pragma unroll
  for (int tj = 0; tj < 4; ++tj) bj[tj] = bproj[n0 + wn * 64 + tj * 16 + l16];
#pragma unroll
  for (int ti = 0; ti < 2; ++ti)
#pragma unroll
    for (int i = 0; i < 4; ++i) {
      size_t rowoff = (size_t)(m0 + wm * 32 + ti * 16 + quad * 4 + i) * 512;
#pragma unroll
      for (int tj = 0; tj < 4; ++tj)
        out[rowoff + n0 + wn * 64 + tj * 16 + l16] = acc[ti][tj][i] + bj[tj];
    }
}

// =====================================================================
extern "C" void kernel_launch(void* const* d_in, const int* in_sizes, int n_in,
                              void* d_out, int out_size, void* d_ws, size_t ws_size,
                              hipStream_t stream) {
  const float* x     = (const float*)d_in[0];   // (2048, 64, 512)
  const float* wqkv  = (const float*)d_in[1];   // (1536, 512)
  const float* bqkv  = (const float*)d_in[2];   // (1536,)
  const float* wproj = (const float*)d_in[3];   // (512, 512)
  const float* bproj = (const float*)d_in[4];   // (512,)
  const float* btab  = (const float*)d_in[5];   // (7200, 8)
  // d_in[6] = rel_idx -- recomputed analytically in-kernel, not read.
  float* out = (float*)d_out;

  short* wq_b = (short*)d_ws;            // 786,432 bf16
  short* wp_b = wq_b + 786432;           // 262,144 bf16
  short* attn = wp_b + 262144;           // 67,108,864 bf16 (~128 MB); ws use ~130 MB

  prep_weights<<<256, 256, 0, stream>>>(wqkv, wproj, wq_b, wp_b);
  qkv_attn<<<2048, 1024, 0, stream>>>(x, wq_b, bqkv, btab, attn);
  proj_gemm<<<4096, 512, 0, stream>>>(attn, wp_b, bproj, out);
}

// Round 3
// 1045.156 us; speedup vs baseline: 1.0224x; 1.0224x over previous
//
#include <hip/hip_runtime.h>
#include <stdint.h>

// ---------------- types ----------------
typedef __attribute__((ext_vector_type(8))) short short8;   // 8 x bf16 (4 VGPR) MFMA A/B frag
typedef __attribute__((ext_vector_type(4))) short short4v;  // 8B packed LDS write
typedef __attribute__((ext_vector_type(4))) float float4v;  // MFMA C/D frag

__device__ __forceinline__ short f2bf(float f) {
  uint32_t u = __builtin_bit_cast(uint32_t, f);
  u += 0x7FFFu + ((u >> 16) & 1u);   // round-to-nearest-even
  return (short)(u >> 16);
}

// async global->LDS, 16B per lane, wave-uniform LDS base
__device__ __forceinline__ void gl_lds16(const short* g, short* l) {
  __builtin_amdgcn_global_load_lds(
      (const __attribute__((address_space(1))) unsigned int*)g,
      (__attribute__((address_space(3))) unsigned int*)l, 16, 0, 0);
}

// =====================================================================
// LDS swizzle scheme (all row-major short buffers, 16B-unit XOR):
//   element (row, k) stored at row*64 + (k ^ ((row&7)<<3))   [k in shorts]
// b128 reads use two per-lane bases (even/odd 32-short granule):
//   offE = ((quad ^ (r&3))<<3) | ((r>>2)<<5),  offO = offE ^ 32,  r = l16&7
// =====================================================================

// =====================================================================
// Kernel 1: convert weights to bf16 in workspace
// =====================================================================
__global__ void prep_weights(const float* __restrict__ wq, const float* __restrict__ wp,
                             short* __restrict__ wq_b, short* __restrict__ wp_b) {
  int i = blockIdx.x * blockDim.x + threadIdx.x;
  int stride = gridDim.x * blockDim.x;
  for (int j = i; j < 786432 / 4; j += stride) {
    float4 v = ((const float4*)wq)[j];
    short4v t = {f2bf(v.x), f2bf(v.y), f2bf(v.z), f2bf(v.w)};
    ((short4v*)wq_b)[j] = t;
  }
  for (int j = i; j < 262144 / 4; j += stride) {
    float4 v = ((const float4*)wp)[j];
    short4v t = {f2bf(v.x), f2bf(v.y), f2bf(v.z), f2bf(v.w)};
    ((short4v*)wp_b)[j] = t;
  }
}

// =====================================================================
// Kernel 2: fused QKV-GEMM + window attention.
// PERSISTENT blocks: 512 blocks x 4 windows each (outer vi loop reuses the
// same LDS) -- 4x fewer dispatches/ramps; weight rows go L1/L2-warm across
// windows (each wave re-loads the SAME W rows for every window).
// 1024 threads = 16 waves. Per window: stage X, then 2 rounds of 4 heads:
//   phase1: wave (g,st) computes merged {Qt,Kt,V} strip triple with a
//     3-deep MANUAL weight-prefetch pipeline (explicit rotating regs,
//     statically indexed in the fully-unrolled j loop) so L2/HBM load
//     latency overlaps the previous iterations' 12 MFMAs.
//   phase2: wave -> (head, 16-row strip): S=Q*K^T + analytic earth bias,
//     shfl softmax, P->Qs (wave-local), O=P*Vt, bf16 store.
// LDS: Xs 64K + Qs/Ks/Vt 4 heads x 8K each = 163,840 B. XOR-swizzled.
// =====================================================================
__global__ __launch_bounds__(1024, 4)
void qkv_attn(const float* __restrict__ x, const short* __restrict__ wq,
              const float* __restrict__ bqkv, const float* __restrict__ btab,
              short* __restrict__ attn) {
  __shared__ short Xs[64 * 512];        // 65,536 B
  __shared__ short Qs[4][64 * 64];      // 32,768 B
  __shared__ short Ks[4][64 * 64];      // 32,768 B
  __shared__ short Vt[4][64 * 64];      // 32,768 B   total 163,840 B

  const int blk  = blockIdx.x;     // 0..511
  const int tid  = threadIdx.x;
  const int lane = tid & 63;
  const int w    = tid >> 6;       // wave 0..15
  const int l16  = lane & 15;
  const int quad = lane >> 4;      // 0..3
  const int r    = l16 & 7;
  const int offE = ((quad ^ (r & 3)) << 3) | ((r >> 2) << 5);
  const int offO = offE ^ 32;

  const int g  = w >> 2;   // head offset within round (Q,V) ; K head = g^1
  const int st = w & 3;    // 16-row strip

#pragma unroll 1
  for (int vi = 0; vi < 4; ++vi) {
    const int b   = blk * 4 + vi;
    const int lat = b >> 6;          // MLON = 64

    // ---- stage X window into LDS as bf16 (swizzled write) ----
    const float* xw = x + (size_t)b * (64 * 512);
    for (int c = tid; c < 64 * 128; c += 1024) {   // float4 chunks
      int n = c >> 7, kc = c & 127;
      float4 v = *(const float4*)(xw + n * 512 + kc * 4);
      short4v t = {f2bf(v.x), f2bf(v.y), f2bf(v.z), f2bf(v.w)};
      *(short4v*)&Xs[n * 512 + ((kc * 4) ^ ((n & 7) << 3))] = t;
    }
    __syncthreads();

#pragma unroll 1
    for (int h0 = 0; h0 < 8; h0 += 4) {
      // ---------------- phase 1: QKV GEMMs (strip-merged, prefetched) ----------------
      {
        const int hq = h0 + g;
        const int hk = h0 + (g ^ 1);
        const short* Aq = wq + (size_t)((hq * 64 + st * 16 + l16) * 512) + quad * 8;
        const short* Ak = wq + (size_t)((512 + hk * 64 + st * 16 + l16) * 512) + quad * 8;
        const short* Av = wq + (size_t)((1024 + hq * 64 + st * 16 + l16) * 512) + quad * 8;
        const short* xE = &Xs[l16 * 512 + offE];
        const short* xO = &Xs[l16 * 512 + offO];

        // 3-deep rotating weight prefetch (indices compile-time in unrolled loop)
        short8 wqp[3], wkp[3], wvp[3];
        wqp[0] = *(const short8*)(Aq);      wqp[1] = *(const short8*)(Aq + 32);
        wkp[0] = *(const short8*)(Ak);      wkp[1] = *(const short8*)(Ak + 32);
        wvp[0] = *(const short8*)(Av);      wvp[1] = *(const short8*)(Av + 32);

        float4v aQ[4] = {}, aK[4] = {}, aV[4] = {};
#pragma unroll
        for (int j = 0; j < 16; ++j) {            // kk = j*32
          if (j + 2 < 16) {
            wqp[(j + 2) % 3] = *(const short8*)(Aq + (j + 2) * 32);
            wkp[(j + 2) % 3] = *(const short8*)(Ak + (j + 2) * 32);
            wvp[(j + 2) % 3] = *(const short8*)(Av + (j + 2) * 32);
          }
          const short* xb = (j & 1) ? xO : xE;
          const int xoff = (j >> 1) * 64;
          short8 x0 = *(const short8*)(xb + xoff);
          short8 x1 = *(const short8*)(xb + 8192 + xoff);
          short8 x2 = *(const short8*)(xb + 16384 + xoff);
          short8 x3 = *(const short8*)(xb + 24576 + xoff);
          short8 Wq = wqp[j % 3], Wk = wkp[j % 3], Wv = wvp[j % 3];
          aQ[0] = __builtin_amdgcn_mfma_f32_16x16x32_bf16(Wq, x0, aQ[0], 0, 0, 0);
          aQ[1] = __builtin_amdgcn_mfma_f32_16x16x32_bf16(Wq, x1, aQ[1], 0, 0, 0);
          aQ[2] = __builtin_amdgcn_mfma_f32_16x16x32_bf16(Wq, x2, aQ[2], 0, 0, 0);
          aQ[3] = __builtin_amdgcn_mfma_f32_16x16x32_bf16(Wq, x3, aQ[3], 0, 0, 0);
          aK[0] = __builtin_amdgcn_mfma_f32_16x16x32_bf16(Wk, x0, aK[0], 0, 0, 0);
          aK[1] = __builtin_amdgcn_mfma_f32_16x16x32_bf16(Wk, x1, aK[1], 0, 0, 0);
          aK[2] = __builtin_amdgcn_mfma_f32_16x16x32_bf16(Wk, x2, aK[2], 0, 0, 0);
          aK[3] = __builtin_amdgcn_mfma_f32_16x16x32_bf16(Wk, x3, aK[3], 0, 0, 0);
          aV[0] = __builtin_amdgcn_mfma_f32_16x16x32_bf16(x0, Wv, aV[0], 0, 0, 0);
          aV[1] = __builtin_amdgcn_mfma_f32_16x16x32_bf16(x1, Wv, aV[1], 0, 0, 0);
          aV[2] = __builtin_amdgcn_mfma_f32_16x16x32_bf16(x2, Wv, aV[2], 0, 0, 0);
          aV[3] = __builtin_amdgcn_mfma_f32_16x16x32_bf16(x3, Wv, aV[3], 0, 0, 0);
        }

        // ---- epilogues (identical math; swizzled LDS writes) ----
        float bq[4], bk[4];
#pragma unroll
        for (int i = 0; i < 4; ++i) {
          bq[i] = bqkv[hq * 64 + st * 16 + quad * 4 + i];
          bk[i] = bqkv[512 + hk * 64 + st * 16 + quad * 4 + i];
        }
        short* dq = &Qs[g][0];
        short* dk = &Ks[g ^ 1][0];
        const int swqk = (st * 16 + quad * 4) ^ (r << 3);   // row&7 == r for rows t*16+l16
#pragma unroll
        for (int t = 0; t < 4; ++t) {
          int n = t * 16 + l16;
          short4v pq, pk;
#pragma unroll
          for (int i = 0; i < 4; ++i) {
            pq[i] = f2bf((aQ[t][i] + bq[i]) * 0.125f);   // fold q-scale (exact pow2)
            pk[i] = f2bf(aK[t][i] + bk[i]);
          }
          *(short4v*)&dq[n * 64 + swqk] = pq;  // [n][d] packed, swizzled
          *(short4v*)&dk[n * 64 + swqk] = pk;
        }
        float bv = bqkv[1024 + hq * 64 + st * 16 + l16];
        const int dv = st * 16 + l16;          // Vt row (= d); dv&7 == r
#pragma unroll
        for (int t = 0; t < 4; ++t) {
          short4v pv;
#pragma unroll
          for (int i = 0; i < 4; ++i) pv[i] = f2bf(aV[t][i] + bv);
          *(short4v*)&Vt[g][dv * 64 + ((t * 16 + quad * 4) ^ (r << 3))] = pv;  // [d][m]
        }
      }
      __syncthreads();

      // ---------------- phase 2: attention ----------------
      {
        const int hsel = w >> 2;
        const int h    = h0 + hsel;
        const int n0   = (w & 3) * 16;
        const short* Qb = &Qs[hsel][0];
        const short* Kb = &Ks[hsel][0];
        const short* Vb = &Vt[hsel][0];

        // S = Q * K^T  (K-dim = d = 64)
        float4v s4[4] = {};
#pragma unroll
        for (int j = 0; j < 2; ++j) {
          const int o = j ? offO : offE;
          short8 a = *(const short8*)&Qb[(n0 + l16) * 64 + o];
#pragma unroll
          for (int t = 0; t < 4; ++t) {
            short8 bf = *(const short8*)&Kb[(t * 16 + l16) * 64 + o];
            s4[t] = __builtin_amdgcn_mfma_f32_16x16x32_bf16(a, bf, s4[t], 0, 0, 0);
          }
        }
        // analytic earth bias (skips rel_idx input entirely)
#pragma unroll
        for (int t = 0; t < 4; ++t) {
          int m = t * 16 + l16;
#pragma unroll
          for (int i = 0; i < 4; ++i) {
            int n = n0 + quad * 4 + i;
            int idx = ((n >> 3) - (m >> 3) + 7) * 15 + ((n & 7) - (m & 7) + 7) + lat * 225;
            s4[t][i] += btab[idx * 8 + h];
          }
        }
        // row softmax: row n held at fixed reg i across 16 lanes of the quad
        float p[4][4];
#pragma unroll
        for (int i = 0; i < 4; ++i) {
          float mx = fmaxf(fmaxf(s4[0][i], s4[1][i]), fmaxf(s4[2][i], s4[3][i]));
          mx = fmaxf(mx, __shfl_xor(mx, 1));
          mx = fmaxf(mx, __shfl_xor(mx, 2));
          mx = fmaxf(mx, __shfl_xor(mx, 4));
          mx = fmaxf(mx, __shfl_xor(mx, 8));
          float e0 = __expf(s4[0][i] - mx), e1 = __expf(s4[1][i] - mx);
          float e2 = __expf(s4[2][i] - mx), e3 = __expf(s4[3][i] - mx);
          float sm = e0 + e1 + e2 + e3;
          sm += __shfl_xor(sm, 1);
          sm += __shfl_xor(sm, 2);
          sm += __shfl_xor(sm, 4);
          sm += __shfl_xor(sm, 8);
          float inv = 1.0f / sm;
          p[0][i] = e0 * inv; p[1][i] = e1 * inv; p[2][i] = e2 * inv; p[3][i] = e3 * inv;
        }
        // P -> LDS (overwrite own Q rows; wave-local round trip -- no barrier)
        short* Pw = &Qs[hsel][0];
#pragma unroll
        for (int t = 0; t < 4; ++t)
#pragma unroll
          for (int i = 0; i < 4; ++i) {
            int row = n0 + quad * 4 + i;
            Pw[row * 64 + ((t * 16 + l16) ^ ((row & 7) << 3))] = f2bf(p[t][i]);
          }

        // O = P * V  (K-dim = m = 64)
        float4v o4[4] = {};
#pragma unroll
        for (int j = 0; j < 2; ++j) {
          const int o = j ? offO : offE;
          short8 a = *(const short8*)&Qb[(n0 + l16) * 64 + o];
#pragma unroll
          for (int t = 0; t < 4; ++t) {
            short8 bf = *(const short8*)&Vb[(t * 16 + l16) * 64 + o];
            o4[t] = __builtin_amdgcn_mfma_f32_16x16x32_bf16(a, bf, o4[t], 0, 0, 0);
          }
        }
        // store attn[b][n][h*64 + d] as bf16
        short* ob = attn + (size_t)b * (64 * 512);
#pragma unroll
        for (int t = 0; t < 4; ++t)
#pragma unroll
          for (int i = 0; i < 4; ++i)
            ob[(n0 + quad * 4 + i) * 512 + h * 64 + t * 16 + l16] = f2bf(o4[t][i]);
      }
      __syncthreads();   // protect Qs/Ks/Vt before next head round / re-stage
    }
  }
}

// =====================================================================
// Kernel 3: out = attn(131072x512 bf16) @ w_proj^T + b_proj   (fp32 out)
// PERSISTENT blocks: 1024 blocks x 4 m-tiles each (same n-slab -> B-panel
// and bias reused across tiles; 4x fewer dispatches).
// Per tile: 128x128, BK=64, 8 waves (32x64/wave), double-buffered
// global_load_lds with stage-ahead; both-sides swizzle (linear LDS dest +
// inverse-swizzled global source col + swizzled ds_read) -> conflict-free.
// 64 KB LDS -> 2 blocks/CU = 4 waves/SIMD.
// =====================================================================
__device__ __forceinline__ void stage_tile(const short* __restrict__ ga,
                                           const short* __restrict__ gb,
                                           short* lA, short* lB,
                                           int w, int srow, int scol) {
#pragma unroll
  for (int j = 0; j < 2; ++j) {
    int c = w * 2 + j;   // chunk 0..15, 8 rows each
    gl_lds16(ga + (size_t)(c * 8 + srow) * 512 + scol, &lA[c * 512]);
    gl_lds16(gb + (size_t)(c * 8 + srow) * 512 + scol, &lB[c * 512]);
  }
}

__device__ __forceinline__ void compute_tile(const short* As_, const short* Bs_,
                                             float4v (&acc)[2][4],
                                             int wm, int wn, int l16,
                                             int offE, int offO) {
#pragma unroll
  for (int ks = 0; ks < 2; ++ks) {
    const int o = ks ? offO : offE;
    short8 a[2], bf[4];
#pragma unroll
    for (int ti = 0; ti < 2; ++ti)
      a[ti] = *(const short8*)&As_[(wm * 32 + ti * 16 + l16) * 64 + o];
#pragma unroll
    for (int tj = 0; tj < 4; ++tj)
      bf[tj] = *(const short8*)&Bs_[(wn * 64 + tj * 16 + l16) * 64 + o];
#pragma unroll
    for (int ti = 0; ti < 2; ++ti)
#pragma unroll
      for (int tj = 0; tj < 4; ++tj)
        acc[ti][tj] = __builtin_amdgcn_mfma_f32_16x16x32_bf16(a[ti], bf[tj], acc[ti][tj], 0, 0, 0);
  }
}

__global__ __launch_bounds__(512, 4)
void proj_gemm(const short* __restrict__ attn, const short* __restrict__ wp,
               const float* __restrict__ bproj, float* __restrict__ out) {
  __shared__ short As0[128 * 64];   // 16 KB each; named buffers so alias
  __shared__ short As1[128 * 64];   // analysis lets ds_read(cur) bypass the
  __shared__ short Bs0[128 * 64];   // in-flight gl_lds(next) -> overlap.
  __shared__ short Bs1[128 * 64];   // total 64 KB -> 2 blocks/CU

  // XCD-bijective remap (nwg=1024 = 8*128): wg = xcd*128 + orig/8
  const int orig = blockIdx.x;
  const int wg   = (orig & 7) * 128 + (orig >> 3);
  const int n0   = (wg & 3) * 128;   // n fastest: 4 n-blocks share an A-panel
  const int mp   = wg >> 2;          // 0..255: panel group; m0 = mp*512 + it*128

  const int tid  = threadIdx.x;
  const int lane = tid & 63;
  const int w    = tid >> 6;           // 0..7
  const int l16  = lane & 15;
  const int quad = lane >> 4;
  const int wm   = w >> 1, wn = w & 1; // wave tile: rows wm*32, cols wn*64
  const int r    = l16 & 7;
  const int offE = ((quad ^ (r & 3)) << 3) | ((r >> 2) << 5);
  const int offO = offE ^ 32;

  // staging: lane -> (srow, swizzled global col) so LINEAR lds dest yields
  // the swizzled layout: slot (row, s) holds element k = s ^ ((row&7)<<3)
  const int srow = lane >> 3;                       // 0..7 (== row&7)
  const int scol = ((lane & 7) ^ srow) * 8;         // shorts

  const short* gB = wp + (size_t)n0 * 512;

  float bj[4];
#pragma unroll
  for (int tj = 0; tj < 4; ++tj) bj[tj] = bproj[n0 + wn * 64 + tj * 16 + l16];

#pragma unroll 1
  for (int it = 0; it < 4; ++it) {
    const int m0 = mp * 512 + it * 128;
    const short* gA = attn + (size_t)m0 * 512;

    float4v acc[2][4] = {};

    stage_tile(gA, gB, As0, Bs0, w, srow, scol);
    __syncthreads();
#pragma unroll
    for (int kt = 0; kt < 8; kt += 2) {
      if (kt + 1 < 8) stage_tile(gA + (kt + 1) * 64, gB + (kt + 1) * 64, As1, Bs1, w, srow, scol);
      compute_tile(As0, Bs0, acc, wm, wn, l16, offE, offO);
      __syncthreads();
      if (kt + 2 < 8) stage_tile(gA + (kt + 2) * 64, gB + (kt + 2) * 64, As0, Bs0, w, srow, scol);
      compute_tile(As1, Bs1, acc, wm, wn, l16, offE, offO);
      __syncthreads();
    }

#pragma unroll
    for (int ti = 0; ti < 2; ++ti)
#pragma unroll
      for (int i = 0; i < 4; ++i) {
        size_t rowoff = (size_t)(m0 + wm * 32 + ti * 16 + quad * 4 + i) * 512;
#pragma unroll
        for (int tj = 0; tj < 4; ++tj)
          out[rowoff + n0 + wn * 64 + tj * 16 + l16] = acc[ti][tj][i] + bj[tj];
      }
  }
}

// =====================================================================
extern "C" void kernel_launch(void* const* d_in, const int* in_sizes, int n_in,
                              void* d_out, int out_size, void* d_ws, size_t ws_size,
                              hipStream_t stream) {
  const float* x     = (const float*)d_in[0];   // (2048, 64, 512)
  const float* wqkv  = (const float*)d_in[1];   // (1536, 512)
  const float* bqkv  = (const float*)d_in[2];   // (1536,)
  const float* wproj = (const float*)d_in[3];   // (512, 512)
  const float* bproj = (const float*)d_in[4];   // (512,)
  const float* btab  = (const float*)d_in[5];   // (7200, 8)
  // d_in[6] = rel_idx -- recomputed analytically in-kernel, not read.
  float* out = (float*)d_out;

  short* wq_b = (short*)d_ws;            // 786,432 bf16
  short* wp_b = wq_b + 786432;           // 262,144 bf16
  short* attn = wp_b + 262144;           // 67,108,864 bf16 (~128 MB); ws use ~130 MB

  prep_weights<<<256, 256, 0, stream>>>(wqkv, wproj, wq_b, wp_b);
  qkv_attn<<<512, 1024, 0, stream>>>(x, wq_b, bqkv, btab, attn);
  proj_gemm<<<1024, 512, 0, stream>>>(attn, wp_b, bproj, out);
}